// Round 7
// baseline (10084.548 us; speedup 1.0000x reference)
//
#include <hip/hip_runtime.h>
#include <hip/hip_fp16.h>

#define F_DIM 510
#define KP    512      // padded K
#define B_SZ  256
#define T_ST  512
#define MB    64       // batch rows per chunk
#define NWG   256
#define R1    8        // h1 ring depth
#define R2    4        // h2 ring depth

typedef _Float16 h8 __attribute__((ext_vector_type(8)));
typedef float    f4 __attribute__((ext_vector_type(4)));
typedef unsigned long long u64;

__device__ __forceinline__ float sigm(float v)   { return 1.0f / (1.0f + __expf(-v)); }
__device__ __forceinline__ float tanh_f(float v) { return 1.0f - 2.0f / (__expf(2.0f * v) + 1.0f); }

__global__ void init_kernel(float* __restrict__ out, const float* __restrict__ b_lin,
                            int* __restrict__ flags) {
  int i = blockIdx.x * blockDim.x + threadIdx.x;
  if (i < NWG) flags[i] = 0;
  if (i < B_SZ * T_ST) out[i] = b_lin[0];
}

// stage fp32 x [MB][F_DIM] -> LDS fp16 [MB][KP], XOR-swizzled (plain cached loads)
__device__ __forceinline__ void stage_x(char* st, const float* __restrict__ src, int tid) {
  #pragma unroll
  for (int i = 0; i < 16; ++i) {
    int c  = tid + (i << 8);
    int m  = c >> 6;
    int kb = (c & 63) << 3;
    h8 v;
    const float* s = src + m * F_DIM + kb;
    if (kb + 8 <= F_DIM) {
      #pragma unroll
      for (int e = 0; e < 4; ++e) {
        float2 p = *(const float2*)(s + 2 * e);
        v[2 * e]     = (_Float16)p.x;
        v[2 * e + 1] = (_Float16)p.y;
      }
    } else {
      #pragma unroll
      for (int e = 0; e < 8; ++e) v[e] = (_Float16)((kb + e < F_DIM) ? s[e] : 0.0f);
    }
    int byte = ((m * KP + kb) << 1) ^ ((m & 7) << 4);
    *(h8*)(st + byte) = v;
  }
}

// issue 32 pipelined coherent 8B loads into registers (64 KiB tile / 256 threads)
__device__ __forceinline__ void load_h32(u64* v, const _Float16* __restrict__ src, int tid) {
  const u64* s = (const u64*)src;
  #pragma unroll
  for (int i = 0; i < 32; ++i)
    v[i] = __hip_atomic_load(s + tid + (i << 8),
                             __ATOMIC_RELAXED, __HIP_MEMORY_SCOPE_AGENT);
}

// write registers -> LDS fp16 [MB][KP], XOR-swizzled
__device__ __forceinline__ void write_h32(char* st, const u64* v, int tid) {
  #pragma unroll
  for (int i = 0; i < 32; ++i) {
    int c  = tid + (i << 8);          // 8B-chunk index
    int m  = c >> 7;                  // row 0..63
    int kc = c & 127;                 // 8B chunk within 1024B row
    int byte = (m * 1024 + (kc << 3)) ^ ((m & 7) << 4);
    *(u64*)(st + byte) = v[i];
  }
}

__device__ __forceinline__ void gemm_tile(f4* acc, const char* sm, const h8* wf,
                                          int col, int krow) {
  #pragma unroll
  for (int ks = 0; ks < 16; ++ks) {
    #pragma unroll
    for (int mt = 0; mt < 4; ++mt) {
      int lin = mt * 16384 + col * 1024 + ks * 64 + krow * 16;
      h8 af = *(const h8*)(sm + (lin ^ ((col & 7) << 4)));
      acc[mt] = __builtin_amdgcn_mfma_f32_16x16x32_f16(af, wf[ks], acc[mt], 0, 0, 0);
    }
  }
}

// all-wave poll: lane<32 watches the 32 L1 flags (>= thr_lo), lane>=32 the 32 L2
// flags (>= thr_hi).
__device__ __forceinline__ void poll_flags(const int* fl, int thr_lo, int thr_hi, int lane) {
  const int thr = (lane < 32) ? thr_lo : thr_hi;
  const int* p = fl + lane;
  while (true) {
    int v = __hip_atomic_load(p, __ATOMIC_RELAXED, __HIP_MEMORY_SCOPE_AGENT);
    if (__all(v >= thr)) break;
  }
}

__launch_bounds__(256, 1)
__global__ void lstm_kernel(
    const float* __restrict__ x,
    const float* __restrict__ w_ih1, const float* __restrict__ w_hh1,
    const float* __restrict__ b_ih1, const float* __restrict__ b_hh1,
    const float* __restrict__ w_ih2, const float* __restrict__ w_hh2,
    const float* __restrict__ b_ih2, const float* __restrict__ b_hh2,
    const float* __restrict__ w_lin,
    float* __restrict__ out, char* __restrict__ ws)
{
  __shared__ __align__(16) char smem[MB * KP * 2];   // 64 KiB operand stage
  float (*gbuf)[MB][17] = (float (*)[MB][17])smem;   // aliased gate exchange

  int* flags   = (int*)ws;                                        // [4][64]
  _Float16* h1 = (_Float16*)(ws + 4096);                          // [R1][B_SZ][KP]
  _Float16* h2 = (_Float16*)(ws + 4096 + (size_t)R1 * B_SZ * KP * 2);  // [R2][B_SZ][KP]

  const int tid  = threadIdx.x;
  const int lane = tid & 63;
  const int wave = tid >> 6;           // wave owns gate type (i,f,g,o)
  const int wg   = blockIdx.x;
  const int xcd   = wg & 7;            // perf heuristic only (round-robin XCD)
  const bool isL2 = (xcd & 1) != 0;
  const int mb    = xcd >> 1;          // batch chunk 0..3
  const int nb    = wg >> 3;           // hidden block 0..31
  int* flags_c    = flags + (mb << 6);
  const int my_flag = (mb << 6) + (isL2 ? 32 : 0) + nb;

  const int j0   = nb << 4;
  const int col  = lane & 15;
  const int krow = lane >> 4;
  const int jj   = j0 + col;
  const bool jvalid = (jj < F_DIM);

  const float* wA = isL2 ? w_ih2 : w_ih1;
  const float* wB = isL2 ? w_hh2 : w_hh1;
  const float* bi = isL2 ? b_ih2 : b_ih1;
  const float* bh = isL2 ? b_hh2 : b_hh1;
  const int nrow  = wave * F_DIM + jj;

  // Weights resident in registers as MFMA B-fragments: B[k][n] = W[n][k]
  h8 wfA[16], wfB[16];
  #pragma unroll
  for (int ks = 0; ks < 16; ++ks) {
    h8 a, b;
    #pragma unroll
    for (int e = 0; e < 8; ++e) {
      int k = (ks << 5) + (krow << 3) + e;
      bool ok = jvalid && (k < F_DIM);
      a[e] = (_Float16)(ok ? wA[nrow * F_DIM + k] : 0.0f);
      b[e] = (_Float16)(ok ? wB[nrow * F_DIM + k] : 0.0f);
    }
    wfA[ks] = a; wfB[ks] = b;
  }
  const float bias = jvalid ? (bi[nrow] + bh[nrow]) : 0.0f;

  // cell-update mapping: thread owns (row = tid>>2, cols j0 + (tid&3)*4 .. +3)
  const int urow = tid >> 2;
  const int cg   = tid & 3;
  float wl4[4];
  #pragma unroll
  for (int cc = 0; cc < 4; ++cc) {
    int j = j0 + (cg << 2) + cc;
    wl4[cc] = (isL2 && j < F_DIM) ? w_lin[j] : 0.0f;
  }

  float cst[4] = {0.f, 0.f, 0.f, 0.f};
  u64 hstg[32];
  f4 acc[4];

  if (!isL2) {
    // ================= Layer-1 pipeline =================
    // prologue: acc = bias + x(0) @ Wih^T
    #pragma unroll
    for (int mt = 0; mt < 4; ++mt) acc[mt] = (f4){bias, bias, bias, bias};
    stage_x(smem, x + (size_t)mb * MB * F_DIM, tid);
    __syncthreads();
    gemm_tile(acc, smem, wfA, col, krow);

    for (int t = 0; t < T_ST; ++t) {
      if (t > 0) {
        // recurrent path: h1(t-1) @ Whh^T  (x-GEMM for step t already in acc)
        poll_flags(flags_c, t, t - 7, lane);
        load_h32(hstg, h1 + ((size_t)((t - 1) % R1) * B_SZ + mb * MB) * KP, tid);
        __builtin_amdgcn_sched_barrier(0);
        __syncthreads();             // prior gemm readers done with smem
        write_h32(smem, hstg, tid);
        __syncthreads();
        gemm_tile(acc, smem, wfB, col, krow);
      }
      __syncthreads();               // gemm readers done; smem -> gbuf

      // gate exchange
      #pragma unroll
      for (int mt = 0; mt < 4; ++mt) {
        #pragma unroll
        for (int r = 0; r < 4; ++r)
          gbuf[wave][mt * 16 + (krow << 2) + r][col] = acc[mt][r];
      }
      __syncthreads();

      // cell update + h1 store
      float hv4[4];
      #pragma unroll
      for (int cc = 0; cc < 4; ++cc) {
        int c = (cg << 2) + cc;
        float gi = gbuf[0][urow][c];
        float gf = gbuf[1][urow][c];
        float gg = gbuf[2][urow][c];
        float go = gbuf[3][urow][c];
        float cn = sigm(gf) * cst[cc] + sigm(gi) * tanh_f(gg);
        cst[cc] = cn;
        hv4[cc] = sigm(go) * tanh_f(cn);
      }
      u64 hb;
      {
        unsigned int s0 = __builtin_bit_cast(unsigned short, (_Float16)hv4[0]);
        unsigned int s1 = __builtin_bit_cast(unsigned short, (_Float16)hv4[1]);
        unsigned int s2 = __builtin_bit_cast(unsigned short, (_Float16)hv4[2]);
        unsigned int s3 = __builtin_bit_cast(unsigned short, (_Float16)hv4[3]);
        hb = (u64)(s0 | (s1 << 16)) | ((u64)(s2 | (s3 << 16)) << 32);
      }
      int bg = mb * MB + urow;
      __hip_atomic_store((u64*)(h1 + (size_t)(t % R1) * B_SZ * KP +
                                (size_t)bg * KP + j0 + (cg << 2)), hb,
                         __ATOMIC_RELAXED, __HIP_MEMORY_SCOPE_AGENT);
      asm volatile("s_waitcnt vmcnt(0)" ::: "memory");
      __syncthreads();
      if (tid == 0)
        __hip_atomic_store(&flags[my_flag], t + 1,
                           __ATOMIC_RELAXED, __HIP_MEMORY_SCOPE_AGENT);

      // off-critical-path: precompute x-GEMM for step t+1
      if (t + 1 < T_ST) {
        #pragma unroll
        for (int mt = 0; mt < 4; ++mt) acc[mt] = (f4){bias, bias, bias, bias};
        stage_x(smem, x + ((size_t)(t + 1) * B_SZ + mb * MB) * F_DIM, tid);
        __syncthreads();
        gemm_tile(acc, smem, wfA, col, krow);
      }
    }
  } else {
    // ================= Layer-2 pipeline =================
    for (int t = 0; t < T_ST; ++t) {
      #pragma unroll
      for (int mt = 0; mt < 4; ++mt) acc[mt] = (f4){bias, bias, bias, bias};

      // single poll: L1 done step t (flag>=t+1); L2 peers done step t-1 (flag>=t)
      poll_flags(flags_c, t + 1, t, lane);
      load_h32(hstg, h1 + ((size_t)(t % R1) * B_SZ + mb * MB) * KP, tid);
      __builtin_amdgcn_sched_barrier(0);
      __syncthreads();               // prev-iter gbuf readers done with smem
      write_h32(smem, hstg, tid);
      __syncthreads();
      if (t > 0) {                   // issue h2(t-1) loads; latency hides under GEMM1
        load_h32(hstg, h2 + ((size_t)((t - 1) % R2) * B_SZ + mb * MB) * KP, tid);
        __builtin_amdgcn_sched_barrier(0);
      }
      gemm_tile(acc, smem, wfA, col, krow);
      __syncthreads();               // gemm1 readers done
      if (t > 0) {
        write_h32(smem, hstg, tid);
        __syncthreads();
        gemm_tile(acc, smem, wfB, col, krow);
        __syncthreads();
      }

      // gate exchange
      #pragma unroll
      for (int mt = 0; mt < 4; ++mt) {
        #pragma unroll
        for (int r = 0; r < 4; ++r)
          gbuf[wave][mt * 16 + (krow << 2) + r][col] = acc[mt][r];
      }
      __syncthreads();

      // cell update + h2 store
      float hv4[4];
      #pragma unroll
      for (int cc = 0; cc < 4; ++cc) {
        int c = (cg << 2) + cc;
        float gi = gbuf[0][urow][c];
        float gf = gbuf[1][urow][c];
        float gg = gbuf[2][urow][c];
        float go = gbuf[3][urow][c];
        float cn = sigm(gf) * cst[cc] + sigm(gi) * tanh_f(gg);
        cst[cc] = cn;
        hv4[cc] = sigm(go) * tanh_f(cn);
      }
      u64 hb;
      {
        unsigned int s0 = __builtin_bit_cast(unsigned short, (_Float16)hv4[0]);
        unsigned int s1 = __builtin_bit_cast(unsigned short, (_Float16)hv4[1]);
        unsigned int s2 = __builtin_bit_cast(unsigned short, (_Float16)hv4[2]);
        unsigned int s3 = __builtin_bit_cast(unsigned short, (_Float16)hv4[3]);
        hb = (u64)(s0 | (s1 << 16)) | ((u64)(s2 | (s3 << 16)) << 32);
      }
      int bg = mb * MB + urow;
      __hip_atomic_store((u64*)(h2 + (size_t)(t % R2) * B_SZ * KP +
                                (size_t)bg * KP + j0 + (cg << 2)), hb,
                         __ATOMIC_RELAXED, __HIP_MEMORY_SCOPE_AGENT);
      asm volatile("s_waitcnt vmcnt(0)" ::: "memory");
      __syncthreads();
      if (tid == 0)
        __hip_atomic_store(&flags[my_flag], t + 1,
                           __ATOMIC_RELAXED, __HIP_MEMORY_SCOPE_AGENT);

      // contended output atomics AFTER the flag -> off the critical path
      float part = hv4[0] * wl4[0] + hv4[1] * wl4[1] + hv4[2] * wl4[2] + hv4[3] * wl4[3];
      part += __shfl_xor(part, 1);
      part += __shfl_xor(part, 2);
      if ((tid & 3) == 0) atomicAdd(out + (size_t)bg * T_ST + t, part);
    }
  }
}

extern "C" void kernel_launch(void* const* d_in, const int* in_sizes, int n_in,
                              void* d_out, int out_size, void* d_ws, size_t ws_size,
                              hipStream_t stream) {
  (void)in_sizes; (void)n_in; (void)out_size; (void)ws_size;
  const float* x     = (const float*)d_in[0];
  const float* w_ih1 = (const float*)d_in[1];
  const float* w_hh1 = (const float*)d_in[2];
  const float* b_ih1 = (const float*)d_in[3];
  const float* b_hh1 = (const float*)d_in[4];
  const float* w_ih2 = (const float*)d_in[5];
  const float* w_hh2 = (const float*)d_in[6];
  const float* b_ih2 = (const float*)d_in[7];
  const float* b_hh2 = (const float*)d_in[8];
  const float* w_lin = (const float*)d_in[9];
  const float* b_lin = (const float*)d_in[10];
  float* out = (float*)d_out;
  char* ws   = (char*)d_ws;

  hipLaunchKernelGGL(init_kernel, dim3((B_SZ * T_ST + 255) / 256), dim3(256), 0, stream,
                     out, b_lin, (int*)ws);
  hipLaunchKernelGGL(lstm_kernel, dim3(NWG), dim3(256), 0, stream,
                     x, w_ih1, w_hh1, b_ih1, b_hh1,
                     w_ih2, w_hh2, b_ih2, b_hh2,
                     w_lin, out, ws);
}

// Round 8
// 9615.272 us; speedup vs baseline: 1.0488x; 1.0488x over previous
//
#include <hip/hip_runtime.h>
#include <hip/hip_fp16.h>

#define F_DIM 510
#define KP    512      // padded K
#define B_SZ  256
#define T_ST  512
#define MB    64       // batch rows per chunk
#define NWG   256
#define R1    8        // h1 ring depth
#define R2    4        // h2 ring depth

typedef _Float16 h8 __attribute__((ext_vector_type(8)));
typedef float    f4 __attribute__((ext_vector_type(4)));
typedef unsigned long long u64;

__device__ __forceinline__ float sigm(float v)   { return 1.0f / (1.0f + __expf(-v)); }
__device__ __forceinline__ float tanh_f(float v) { return 1.0f - 2.0f / (__expf(2.0f * v) + 1.0f); }

__global__ void init_kernel(float* __restrict__ out, const float* __restrict__ b_lin,
                            int* __restrict__ flags) {
  int i = blockIdx.x * blockDim.x + threadIdx.x;
  if (i < NWG) flags[i] = 0;
  if (i < B_SZ * T_ST) out[i] = b_lin[0];
}

// stage fp32 x [MB][F_DIM] -> LDS fp16 [MB][KP], XOR-swizzled (plain cached loads)
__device__ __forceinline__ void stage_x(char* st, const float* __restrict__ src, int tid) {
  #pragma unroll
  for (int i = 0; i < 16; ++i) {
    int c  = tid + (i << 8);
    int m  = c >> 6;
    int kb = (c & 63) << 3;
    h8 v;
    const float* s = src + m * F_DIM + kb;
    if (kb + 8 <= F_DIM) {
      #pragma unroll
      for (int e = 0; e < 4; ++e) {
        float2 p = *(const float2*)(s + 2 * e);
        v[2 * e]     = (_Float16)p.x;
        v[2 * e + 1] = (_Float16)p.y;
      }
    } else {
      #pragma unroll
      for (int e = 0; e < 8; ++e) v[e] = (_Float16)((kb + e < F_DIM) ? s[e] : 0.0f);
    }
    int byte = ((m * KP + kb) << 1) ^ ((m & 7) << 4);
    *(h8*)(st + byte) = v;
  }
}

// issue 32 pipelined coherent 8B loads into registers (64 KiB tile / 256 threads)
__device__ __forceinline__ void load_h32(u64* v, const _Float16* __restrict__ src, int tid) {
  const u64* s = (const u64*)src;
  #pragma unroll
  for (int i = 0; i < 32; ++i)
    v[i] = __hip_atomic_load(s + tid + (i << 8),
                             __ATOMIC_RELAXED, __HIP_MEMORY_SCOPE_AGENT);
}

// write registers -> LDS fp16 [MB][KP], XOR-swizzled
__device__ __forceinline__ void write_h32(char* st, const u64* v, int tid) {
  #pragma unroll
  for (int i = 0; i < 32; ++i) {
    int c  = tid + (i << 8);          // 8B-chunk index
    int m  = c >> 7;                  // row 0..63
    int kc = c & 127;                 // 8B chunk within 1024B row
    int byte = (m * 1024 + (kc << 3)) ^ ((m & 7) << 4);
    *(u64*)(st + byte) = v[i];
  }
}

// K-split gemm: this wave covers K-slice [kh*256, kh*256+256) for 2 gates.
// Each A-fragment read feeds 2 MFMAs (gate pair) -> half the LDS reads.
__device__ __forceinline__ void gemm_tile2(f4 (*acc)[4], const char* sm,
                                           const h8 wf[2][8], int col, int krow, int kh) {
  #pragma unroll
  for (int ks = 0; ks < 8; ++ks) {
    #pragma unroll
    for (int mt = 0; mt < 4; ++mt) {
      int lin = mt * 16384 + col * 1024 + (kh * 8 + ks) * 64 + krow * 16;
      h8 af = *(const h8*)(sm + (lin ^ ((col & 7) << 4)));
      acc[0][mt] = __builtin_amdgcn_mfma_f32_16x16x32_f16(af, wf[0][ks], acc[0][mt], 0, 0, 0);
      acc[1][mt] = __builtin_amdgcn_mfma_f32_16x16x32_f16(af, wf[1][ks], acc[1][mt], 0, 0, 0);
    }
  }
}

// all-wave poll: lane<32 watches the 32 L1 flags (>= thr_lo), lane>=32 the 32 L2
// flags (>= thr_hi).
__device__ __forceinline__ void poll_flags(const int* fl, int thr_lo, int thr_hi, int lane) {
  const int thr = (lane < 32) ? thr_lo : thr_hi;
  const int* p = fl + lane;
  while (true) {
    int v = __hip_atomic_load(p, __ATOMIC_RELAXED, __HIP_MEMORY_SCOPE_AGENT);
    if (__all(v >= thr)) break;
  }
}

__launch_bounds__(256, 1)
__global__ void lstm_kernel(
    const float* __restrict__ x,
    const float* __restrict__ w_ih1, const float* __restrict__ w_hh1,
    const float* __restrict__ b_ih1, const float* __restrict__ b_hh1,
    const float* __restrict__ w_ih2, const float* __restrict__ w_hh2,
    const float* __restrict__ b_ih2, const float* __restrict__ b_hh2,
    const float* __restrict__ w_lin,
    float* __restrict__ out, char* __restrict__ ws)
{
  __shared__ __align__(16) char smem[MB * KP * 2];        // 64 KiB operand stage
  __shared__ __align__(16) float part[2][4][16][68];      // [kh][gate][col][row+pad]

  int* flags   = (int*)ws;                                        // [4][64]
  _Float16* h1 = (_Float16*)(ws + 4096);                          // [R1][B_SZ][KP]
  _Float16* h2 = (_Float16*)(ws + 4096 + (size_t)R1 * B_SZ * KP * 2);  // [R2][B_SZ][KP]

  const int tid  = threadIdx.x;
  const int lane = tid & 63;
  const int wave = tid >> 6;
  const int gp   = wave & 1;           // gate pair: gates {2gp, 2gp+1}
  const int kh   = wave >> 1;          // K-half: [kh*256, kh*256+256)
  const int wg   = blockIdx.x;
  const int xcd   = wg & 7;            // perf heuristic only (round-robin XCD)
  const bool isL2 = (xcd & 1) != 0;
  const int mb    = xcd >> 1;          // batch chunk 0..3
  const int nb    = wg >> 3;           // hidden block 0..31
  int* flags_c    = flags + (mb << 6);
  const int my_flag = (mb << 6) + (isL2 ? 32 : 0) + nb;

  const int j0   = nb << 4;
  const int col  = lane & 15;
  const int krow = lane >> 4;
  const int jj   = j0 + col;
  const bool jvalid = (jj < F_DIM);

  const float* wA = isL2 ? w_ih2 : w_ih1;
  const float* wB = isL2 ? w_hh2 : w_hh1;
  const float* bi = isL2 ? b_ih2 : b_ih1;
  const float* bh = isL2 ? b_hh2 : b_hh1;

  // B-fragments: 2 gates x K-half per wave, both matrices (128 VGPR total)
  h8 wfA[2][8], wfB[2][8];
  float bias2[2];
  #pragma unroll
  for (int gl = 0; gl < 2; ++gl) {
    const int g    = gp * 2 + gl;
    const int nrow = g * F_DIM + jj;
    #pragma unroll
    for (int ks = 0; ks < 8; ++ks) {
      h8 a, b;
      #pragma unroll
      for (int e = 0; e < 8; ++e) {
        int k = ((kh * 8 + ks) << 5) + (krow << 3) + e;
        bool ok = jvalid && (k < F_DIM);
        a[e] = (_Float16)(ok ? wA[nrow * F_DIM + k] : 0.0f);
        b[e] = (_Float16)(ok ? wB[nrow * F_DIM + k] : 0.0f);
      }
      wfA[gl][ks] = a; wfB[gl][ks] = b;
    }
    bias2[gl] = (kh == 0 && jvalid) ? (bi[nrow] + bh[nrow]) : 0.0f;
  }

  // cell-update mapping: thread owns (row = tid>>2, cols j0 + (tid&3)*4 .. +3)
  const int urow = tid >> 2;
  const int cg   = tid & 3;
  float wl4[4];
  #pragma unroll
  for (int cc = 0; cc < 4; ++cc) {
    int j = j0 + (cg << 2) + cc;
    wl4[cc] = (isL2 && j < F_DIM) ? w_lin[j] : 0.0f;
  }

  float cst[4] = {0.f, 0.f, 0.f, 0.f};
  u64 hstg[32];
  f4 acc[2][4];

  for (int t = 0; t < T_ST; ++t) {
    #pragma unroll
    for (int gl = 0; gl < 2; ++gl)
      #pragma unroll
      for (int mt = 0; mt < 4; ++mt)
        acc[gl][mt] = (f4){bias2[gl], bias2[gl], bias2[gl], bias2[gl]};

    if (!isL2) {
      // ---- L1 step t: h1(t) = cell(x(t) Wih + h1(t-1) Whh) ----
      if (t > 0) {
        poll_flags(flags_c, t, t - 7, lane);
        load_h32(hstg, h1 + ((size_t)((t - 1) % R1) * B_SZ + mb * MB) * KP, tid);
        __builtin_amdgcn_sched_barrier(0);
      }
      stage_x(smem, x + ((size_t)t * B_SZ + mb * MB) * F_DIM, tid);
      __syncthreads();
      gemm_tile2(acc, smem, wfA, col, krow, kh);   // h1-load latency hides here
      if (t > 0) {
        __syncthreads();             // x-gemm readers done with smem
        write_h32(smem, hstg, tid);
        __syncthreads();
        gemm_tile2(acc, smem, wfB, col, krow, kh);
      }
    } else {
      // ---- L2 step t: h2(t) = cell(h1(t) Wih2 + h2(t-1) Whh2) ----
      poll_flags(flags_c, t + 1, t, lane);
      load_h32(hstg, h1 + ((size_t)(t % R1) * B_SZ + mb * MB) * KP, tid);
      __builtin_amdgcn_sched_barrier(0);
      write_h32(smem, hstg, tid);    // prev-iter smem readers done before sync3
      __syncthreads();
      if (t > 0) {                   // issue h2(t-1) loads; latency hides under GEMM1
        load_h32(hstg, h2 + ((size_t)((t - 1) % R2) * B_SZ + mb * MB) * KP, tid);
        __builtin_amdgcn_sched_barrier(0);
      }
      gemm_tile2(acc, smem, wfA, col, krow, kh);
      if (t > 0) {
        __syncthreads();             // gemm1 readers done
        write_h32(smem, hstg, tid);
        __syncthreads();
        gemm_tile2(acc, smem, wfB, col, krow, kh);
      }
    }
    __syncthreads();                 // gemm done; publish partials

    // partial-sum write: conflict-free contiguous f4 per lane
    #pragma unroll
    for (int gl = 0; gl < 2; ++gl)
      #pragma unroll
      for (int mt = 0; mt < 4; ++mt)
        *(f4*)&part[kh][gp * 2 + gl][col][mt * 16 + (krow << 2)] = acc[gl][mt];
    __syncthreads();

    // cell update: thread -> (urow, 4 cols); gates = part[0] + part[1]
    _Float16* hdst = isL2 ? (h2 + (size_t)(t % R2) * B_SZ * KP)
                          : (h1 + (size_t)(t % R1) * B_SZ * KP);
    float hv4[4];
    #pragma unroll
    for (int cc = 0; cc < 4; ++cc) {
      int c = (cg << 2) + cc;
      float gi = part[0][0][c][urow] + part[1][0][c][urow];
      float gf = part[0][1][c][urow] + part[1][1][c][urow];
      float gg = part[0][2][c][urow] + part[1][2][c][urow];
      float go = part[0][3][c][urow] + part[1][3][c][urow];
      float cn = sigm(gf) * cst[cc] + sigm(gi) * tanh_f(gg);
      cst[cc] = cn;
      hv4[cc] = sigm(go) * tanh_f(cn);
    }
    u64 hb;
    {
      unsigned int s0 = __builtin_bit_cast(unsigned short, (_Float16)hv4[0]);
      unsigned int s1 = __builtin_bit_cast(unsigned short, (_Float16)hv4[1]);
      unsigned int s2 = __builtin_bit_cast(unsigned short, (_Float16)hv4[2]);
      unsigned int s3 = __builtin_bit_cast(unsigned short, (_Float16)hv4[3]);
      hb = (u64)(s0 | (s1 << 16)) | ((u64)(s2 | (s3 << 16)) << 32);
    }
    int bg = mb * MB + urow;
    __hip_atomic_store((u64*)(hdst + (size_t)bg * KP + j0 + (cg << 2)), hb,
                       __ATOMIC_RELAXED, __HIP_MEMORY_SCOPE_AGENT);

    // release: drain own h stores, block-wide join, publish progress
    asm volatile("s_waitcnt vmcnt(0)" ::: "memory");
    __syncthreads();
    if (tid == 0)
      __hip_atomic_store(&flags[my_flag], t + 1,
                         __ATOMIC_RELAXED, __HIP_MEMORY_SCOPE_AGENT);

    // contended output atomics AFTER the flag -> off the critical path
    if (isL2) {
      float part_y = hv4[0] * wl4[0] + hv4[1] * wl4[1] + hv4[2] * wl4[2] + hv4[3] * wl4[3];
      part_y += __shfl_xor(part_y, 1);
      part_y += __shfl_xor(part_y, 2);
      if ((tid & 3) == 0) atomicAdd(out + (size_t)bg * T_ST + t, part_y);
    }
  }
}

extern "C" void kernel_launch(void* const* d_in, const int* in_sizes, int n_in,
                              void* d_out, int out_size, void* d_ws, size_t ws_size,
                              hipStream_t stream) {
  (void)in_sizes; (void)n_in; (void)out_size; (void)ws_size;
  const float* x     = (const float*)d_in[0];
  const float* w_ih1 = (const float*)d_in[1];
  const float* w_hh1 = (const float*)d_in[2];
  const float* b_ih1 = (const float*)d_in[3];
  const float* b_hh1 = (const float*)d_in[4];
  const float* w_ih2 = (const float*)d_in[5];
  const float* w_hh2 = (const float*)d_in[6];
  const float* b_ih2 = (const float*)d_in[7];
  const float* b_hh2 = (const float*)d_in[8];
  const float* w_lin = (const float*)d_in[9];
  const float* b_lin = (const float*)d_in[10];
  float* out = (float*)d_out;
  char* ws   = (char*)d_ws;

  hipLaunchKernelGGL(init_kernel, dim3((B_SZ * T_ST + 255) / 256), dim3(256), 0, stream,
                     out, b_lin, (int*)ws);
  hipLaunchKernelGGL(lstm_kernel, dim3(NWG), dim3(256), 0, stream,
                     x, w_ih1, w_hh1, b_ih1, b_hh1,
                     w_ih2, w_hh2, b_ih2, b_hh2,
                     w_lin, out, ws);
}